// Round 1
// 492.764 us; speedup vs baseline: 1.2030x; 1.2030x over previous
//
#include <hip/hip_runtime.h>
#include <hip/hip_bf16.h>
#include <cstdint>
#include <cstddef>

// Problem constants
#define Bsz 8192
#define Hdim 2048
#define Kdim 4096   // EFF
#define Nall 4096   // 2*H in Wt: rows 0..2047 cand, 2048..4095 gate

// GEMM tiling: 8-phase 256^2 template adapted to dual-output.
// Block tile: 256(m) x 128 h-cols, B-tile = 256 rows (cand|gate interleaved
// per-wave). BK=64, 8 waves (2M x 4N), 128 KiB LDS double-buffered.
#define BM 256
#define BNH 128
#define BK 64
#define NTILES (Kdim / BK)   // 64
#define NITER (NTILES / 2)   // 32

typedef __attribute__((ext_vector_type(8))) short short8;   // 8 bf16
typedef __attribute__((ext_vector_type(4))) short short4v;  // 4 bf16 (8B)
typedef __attribute__((ext_vector_type(4))) float floatx4;

// fp32 -> bf16 bits, round-to-nearest-even
__device__ __forceinline__ short f2bf(float f) {
    unsigned u = __float_as_uint(f);
    unsigned r = (u + 0x7fffu + ((u >> 16) & 1u)) >> 16;
    return (short)(r & 0xffffu);
}

__device__ __forceinline__ float fast_tanh(float x) {
    float e = __expf(2.f * x);
    return 1.f - 2.f / (e + 1.f);
}
__device__ __forceinline__ float fast_sigmoid(float x) {
    return 1.f / (1.f + __expf(-x));
}

// async global->LDS, 16B/lane; LDS dest = wave-uniform base + lane*16
__device__ __forceinline__ void g2l16(const void* g, void* l) {
    __builtin_amdgcn_global_load_lds(
        (const __attribute__((address_space(1))) unsigned int*)g,
        (__attribute__((address_space(3))) unsigned int*)l,
        16, 0, 0);
}

// ---------------------------------------------------------------------------
// Kernel 1: combined weight build + transpose.  (unchanged)
// Wt[n][k] (bf16) = n<2048 ? Wc[k][n] + (k>=2048)*Uc[k-2048][n]
//                          : Wg[k][n-2048] + (k>=2048)*Ug[k-2048][n-2048]
// ---------------------------------------------------------------------------
__global__ __launch_bounds__(256) void build_wt(
    const float* __restrict__ Wc, const float* __restrict__ Uc,
    const float* __restrict__ Wg, const float* __restrict__ Ug,
    short* __restrict__ Wt)
{
    __shared__ float tile[32][33];
    const int nt = blockIdx.x * 32;   // n tile base
    const int kt = blockIdx.y * 32;   // k tile base
    const int tx = threadIdx.x & 31;
    const int ty = threadIdx.x >> 5;  // 0..7

    const bool isGate = (nt >= Hdim);
    const float* W = isGate ? Wg : Wc;
    const float* U = isGate ? Ug : Uc;
    const int ncol = isGate ? (nt - Hdim) : nt;

#pragma unroll
    for (int r = 0; r < 32; r += 8) {
        int k = kt + ty + r;
        float v = W[(size_t)k * Hdim + ncol + tx];
        if (k >= Hdim) v += U[(size_t)(k - Hdim) * Hdim + ncol + tx];
        tile[ty + r][tx] = v;
    }
    __syncthreads();
    const int nrow = threadIdx.x >> 3;   // 0..31
    const int kg   = threadIdx.x & 7;    // 0..7
    short4v o;
#pragma unroll
    for (int i = 0; i < 4; ++i) o[i] = f2bf(tile[kg * 4 + i][nrow]);
    *(short4v*)&Wt[(size_t)(nt + nrow) * Kdim + kt + kg * 4] = o;
}

// ---------------------------------------------------------------------------
// Kernel 2: Acat[b][k] (bf16) = k<2048 ? x_t[b][k] : state[b][k-2048]  (unchanged)
// ---------------------------------------------------------------------------
__global__ __launch_bounds__(256) void build_acat(
    const float* __restrict__ x, const float* __restrict__ st,
    short* __restrict__ A)
{
    int idx = blockIdx.x * 256 + threadIdx.x;
    int row = idx >> 9;                  // 512 groups of 8 per row
    int c = (idx & 511) * 8;             // wave-uniform branch
    const float* src = (c < Hdim) ? (x + (size_t)row * Hdim + c)
                                  : (st + (size_t)row * Hdim + (c - Hdim));
    float4 v0 = ((const float4*)src)[0];
    float4 v1 = ((const float4*)src)[1];
    short8 o;
    o[0] = f2bf(v0.x); o[1] = f2bf(v0.y); o[2] = f2bf(v0.z); o[3] = f2bf(v0.w);
    o[4] = f2bf(v1.x); o[5] = f2bf(v1.y); o[6] = f2bf(v1.z); o[7] = f2bf(v1.w);
    *(short8*)(A + (size_t)row * Kdim + c) = o;
}

// ---------------------------------------------------------------------------
// Kernel 3: fused GEMM, 8-phase 256^2 schedule (T1+T2+T3+T4+T5).
// B LDS tile rows: wave wn owns [wn*64, wn*64+64); local<32 -> cand col
// n0+wn*32+local, local>=32 -> gate col (Bt row +2048). Gate/cand combine is
// intra-lane in epilogue: acc[i][j] (cand) with acc[i][j+2] (gate).
// LDS k-chunk swizzle: slot = chunk ^ (row&7); linear global_load_lds dest +
// inverse-swizzled global source + swizzled ds_read (both-sides rule).
// ---------------------------------------------------------------------------
__device__ __forceinline__ void rdA4(const short* base, const int i0,
                                     short8 (&aF)[4][2],
                                     const int cs0, const int cs1) {
#pragma unroll
    for (int i = 0; i < 4; ++i) {
        aF[i][0] = *(const short8*)(base + (i0 + i) * 16 * BK + cs0);
        aF[i][1] = *(const short8*)(base + (i0 + i) * 16 * BK + cs1);
    }
}
__device__ __forceinline__ void rdB2(const short* base, const int j0,
                                     short8 (&bF)[2][2],
                                     const int cs0, const int cs1) {
#pragma unroll
    for (int j = 0; j < 2; ++j) {
        bF[j][0] = *(const short8*)(base + (j0 + j) * 16 * BK + cs0);
        bF[j][1] = *(const short8*)(base + (j0 + j) * 16 * BK + cs1);
    }
}
__device__ __forceinline__ void mma16(floatx4 (&acc)[8][4], const int ia,
                                      const int jb, const short8 (&aF)[4][2],
                                      const short8 (&bF)[2][2]) {
#pragma unroll
    for (int i = 0; i < 4; ++i)
#pragma unroll
        for (int j = 0; j < 2; ++j) {
            acc[ia + i][jb + j] = __builtin_amdgcn_mfma_f32_16x16x32_bf16(
                aF[i][0], bF[j][0], acc[ia + i][jb + j], 0, 0, 0);
            acc[ia + i][jb + j] = __builtin_amdgcn_mfma_f32_16x16x32_bf16(
                aF[i][1], bF[j][1], acc[ia + i][jb + j], 0, 0, 0);
        }
}

#define STAGE(srcArr, h, dstBase, dstOff, koff) do {               \
    g2l16(srcArr[h][0] + (koff), (dstBase) + dstOff[h][0]);        \
    g2l16(srcArr[h][1] + (koff), (dstBase) + dstOff[h][1]); } while (0)

#define BAR()   __builtin_amdgcn_s_barrier()
#define LGKM0() asm volatile("s_waitcnt lgkmcnt(0)" ::: "memory")
#define VM6()   asm volatile("s_waitcnt vmcnt(6)" ::: "memory")
#define VM0()   asm volatile("s_waitcnt vmcnt(0)" ::: "memory")
#define PRIO1() __builtin_amdgcn_s_setprio(1)
#define PRIO0() __builtin_amdgcn_s_setprio(0)

__global__ __launch_bounds__(512, 2) void gemm_fused(
    const short* __restrict__ A,    // [8192][4096] bf16
    const short* __restrict__ Bt,   // [4096][4096] bf16 (cand|gate rows)
    const float* __restrict__ st,   // [8192][2048]
    const float* __restrict__ bc, const float* __restrict__ bg,
    const float* __restrict__ lstep,
    float* __restrict__ Hout)       // [8192][2048]
{
    // A buf0 | A buf1 | B buf0 | B buf1 : each 256x64 bf16 = 32 KB -> 128 KB
    __shared__ __attribute__((aligned(16))) short lds[4][256 * BK];
    short* const sA0 = &lds[0][0];
    short* const sA1 = &lds[1][0];
    short* const sB0 = &lds[2][0];
    short* const sB1 = &lds[3][0];

    const int tid  = threadIdx.x;
    const int lane = tid & 63;
    const int w    = tid >> 6;      // 0..7
    const int wm   = w >> 2;        // 0..1
    const int wn   = w & 3;         // 0..3

    // XCD-bijective block swizzle (nwg=512, 512%8==0)
    const int bid = blockIdx.x;
    const int swz = (bid & 7) * 64 + (bid >> 3);
    const int m0 = (swz >> 4) * BM;     // 32 m-blocks
    const int n0 = (swz & 15) * BNH;    // 16 n-blocks (h-cols)

    // ---- staging source pointers (per-lane, pre-swizzled) ----
    const int r8 = lane >> 3;                  // row within 8-row group
    const int c8 = ((lane & 7) ^ r8) * 8;      // inverse-swizzled k-chunk
    const short* aSrc[2][2];
    const short* bSrc[2][2];
    int dstA[2][2], dstB[2][2];                // wave-uniform LDS offsets (shorts)
#pragma unroll
    for (int h = 0; h < 2; ++h)
#pragma unroll
        for (int q = 0; q < 2; ++q) {
            int f = w * 2 + q;                 // 0..15
            // A-half h: rows {0-63,128-191}+h*64 (consumption-group split)
            int ra = f * 8 + h * 64 + (f & 8) * 8;
            // B-half h: rows {0-31,64-95,128-159,192-223}+h*32
            int rb = (f >> 2) * 64 + (f & 3) * 8 + h * 32;
            aSrc[h][q] = A + (size_t)(m0 + ra + r8) * Kdim + c8;
            int lr = rb + r8;
            int btrow = n0 + ((lr >> 6) << 5) + (lr & 31)
                        + ((lr & 32) ? Hdim : 0);
            bSrc[h][q] = Bt + (size_t)btrow * Kdim + c8;
            dstA[h][q] = ra * BK;
            dstB[h][q] = rb * BK;
        }

    // ---- fragment read bases (swizzled ds_read) ----
    const int fr = lane & 15;
    const int j4 = lane >> 4;                  // 0..3
    const int cs0 = ((j4 ^ (fr & 7)) * 8);     // ks=0 chunk (shorts)
    const int cs1 = (((4 + j4) ^ (fr & 7)) * 8);
    const short* A0f = sA0 + (wm * 128 + fr) * BK;
    const short* A1f = sA1 + (wm * 128 + fr) * BK;
    const short* B0f = sB0 + (wn * 64 + fr) * BK;
    const short* B1f = sB1 + (wn * 64 + fr) * BK;

    floatx4 acc[8][4];
#pragma unroll
    for (int i = 0; i < 8; ++i)
#pragma unroll
        for (int j = 0; j < 4; ++j) {
            floatx4 z = {0.f, 0.f, 0.f, 0.f};
            acc[i][j] = z;
        }
    short8 aF[4][2], bLo[2][2], bHi[2][2];

    // ---- prologue: t0 fully (8 loads), t1 minus A-h1 (6 loads) ----
    STAGE(aSrc, 0, sA0, dstA, 0);
    STAGE(aSrc, 1, sA0, dstA, 0);
    STAGE(bSrc, 0, sB0, dstB, 0);
    STAGE(bSrc, 1, sB0, dstB, 0);
    STAGE(aSrc, 0, sA1, dstA, BK);
    STAGE(bSrc, 0, sB1, dstB, BK);
    STAGE(bSrc, 1, sB1, dstB, BK);
    VM6();                  // t0 landed; t1's 3 half-tiles in flight
    BAR();

    // ---- main loop: 2 K-tiles / iteration, 8 phases ----
    for (int it = 0; it < NITER; ++it) {
        const bool nl = (it < NITER - 1);
        const int k1  = (2 * it + 1) * BK;   // tile t1 (A-h1 late stage)
        const int k02 = (2 * it + 2) * BK;   // tile t0+2 -> buf0
        const int k12 = (2 * it + 3) * BK;   // tile t1+2 -> buf1

        // P1: t0 m0-3 x n0-1 ; stage A-h1(t1)->buf1
        rdA4(A0f, 0, aF, cs0, cs1);
        rdB2(B0f, 0, bLo, cs0, cs1);
        STAGE(aSrc, 1, sA1, dstA, k1);
        BAR(); LGKM0(); PRIO1();
        mma16(acc, 0, 0, aF, bLo);
        PRIO0(); BAR();

        // P2: t0 m0-3 x n2-3 ; stage A-h0(t0+2)->buf0   [A-h0 read done P1]
        rdB2(B0f, 2, bHi, cs0, cs1);
        if (nl) { STAGE(aSrc, 0, sA0, dstA, k02); }
        BAR(); LGKM0(); PRIO1();
        mma16(acc, 0, 2, aF, bHi);
        PRIO0(); BAR();

        // P3: t0 m4-7 x n0-1 ; stage B-h0(t0+2)->buf0   [B-h0 read done P1]
        rdA4(A0f, 4, aF, cs0, cs1);
        if (nl) { STAGE(bSrc, 0, sB0, dstB, k02); }
        BAR(); LGKM0(); PRIO1();
        mma16(acc, 4, 0, aF, bLo);
        PRIO0(); BAR();

        // P4: t0 m4-7 x n2-3 ; stage B-h1(t0+2)->buf0 ; counted vmcnt
        if (nl) { STAGE(bSrc, 1, sB0, dstB, k02); VM6(); }
        else    { VM0(); }               // drain: t1 fully landed
        BAR(); PRIO1();
        mma16(acc, 4, 2, aF, bHi);
        PRIO0(); BAR();

        // P5: t1 m0-3 x n0-1 ; stage A-h1(t0+2)->buf0   [A-h1 read done P3]
        rdA4(A1f, 0, aF, cs0, cs1);
        rdB2(B1f, 0, bLo, cs0, cs1);
        if (nl) { STAGE(aSrc, 1, sA0, dstA, k02); }
        BAR(); LGKM0(); PRIO1();
        mma16(acc, 0, 0, aF, bLo);
        PRIO0(); BAR();

        // P6: t1 m0-3 x n2-3 ; stage A-h0(t1+2)->buf1
        rdB2(B1f, 2, bHi, cs0, cs1);
        if (nl) { STAGE(aSrc, 0, sA1, dstA, k12); }
        BAR(); LGKM0(); PRIO1();
        mma16(acc, 0, 2, aF, bHi);
        PRIO0(); BAR();

        // P7: t1 m4-7 x n0-1 ; stage B-h0(t1+2)->buf1
        rdA4(A1f, 4, aF, cs0, cs1);
        if (nl) { STAGE(bSrc, 0, sB1, dstB, k12); }
        BAR(); LGKM0(); PRIO1();
        mma16(acc, 4, 0, aF, bLo);
        PRIO0(); BAR();

        // P8: t1 m4-7 x n2-3 ; stage B-h1(t1+2)->buf1 ; counted vmcnt
        if (nl) { STAGE(bSrc, 1, sB1, dstB, k12); VM6(); }
        BAR(); PRIO1();
        mma16(acc, 4, 2, aF, bHi);
        PRIO0(); BAR();
    }

    // ---- epilogue: gating, intra-lane cand(j) x gate(j+2) ----
    // C/D layout: col=lane&15, row=(lane>>4)*4+reg  [m89/m91]
    const int cn = lane & 15;
    const int cr = j4 * 4;
    float bcv[2], bgv[2], alv[2];
#pragma unroll
    for (int j = 0; j < 2; ++j) {
        int col = n0 + wn * 32 + j * 16 + cn;
        bcv[j] = bc[col];
        bgv[j] = bg[col];
        alv[j] = __expf(-__expf(-lstep[col]));
    }
#pragma unroll
    for (int i = 0; i < 8; ++i) {
        int rowb = m0 + wm * 128 + i * 16 + cr;
#pragma unroll
        for (int r = 0; r < 4; ++r) {
            int row = rowb + r;
            const float* sp = st + (size_t)row * Hdim;
            float* hp = Hout + (size_t)row * Hdim;
#pragma unroll
            for (int j = 0; j < 2; ++j) {
                int col = n0 + wn * 32 + j * 16 + cn;
                float cand = fast_tanh(acc[i][j][r] + bcv[j]);
                float gate = fast_sigmoid(acc[i][j + 2][r] + bgv[j]);
                float al = alv[j];
                hp[col] = al * sp[col] + (1.f - al) * gate * cand;
            }
        }
    }
}

// ---------------------------------------------------------------------------
// Kernel 4: LayerNorm over h rows. One block per batch row.  (unchanged)
// ---------------------------------------------------------------------------
__global__ __launch_bounds__(256) void ln_k(
    const float* __restrict__ h, const float* __restrict__ gam,
    const float* __restrict__ bet, float* __restrict__ out)
{
    const int b = blockIdx.x;
    const int t = threadIdx.x;
    const int n0 = t * 8;
    const float* hp = h + (size_t)b * Hdim + n0;

    float4 v0 = ((const float4*)hp)[0];
    float4 v1 = ((const float4*)hp)[1];
    float hv[8] = {v0.x, v0.y, v0.z, v0.w, v1.x, v1.y, v1.z, v1.w};
    float sum = 0.f, ss = 0.f;
#pragma unroll
    for (int i = 0; i < 8; ++i) { sum += hv[i]; ss += hv[i] * hv[i]; }

#pragma unroll
    for (int off = 32; off > 0; off >>= 1) {
        sum += __shfl_down(sum, off);
        ss  += __shfl_down(ss, off);
    }
    __shared__ float red[2][4];
    if ((t & 63) == 0) { red[0][t >> 6] = sum; red[1][t >> 6] = ss; }
    __syncthreads();
    sum = red[0][0] + red[0][1] + red[0][2] + red[0][3];
    ss  = red[1][0] + red[1][1] + red[1][2] + red[1][3];

    const float inv = 1.f / (float)Hdim;
    float mu = sum * inv;
    float var = ss * inv - mu * mu;
    float rs = rsqrtf(var + 1e-5f);

    float* op = out + (size_t)b * Hdim + n0;
#pragma unroll
    for (int i = 0; i < 8; ++i) {
        int n = n0 + i;
        op[i] = (hv[i] - mu) * rs * gam[n] + bet[n];
    }
}

// ---------------------------------------------------------------------------
extern "C" void kernel_launch(void* const* d_in, const int* in_sizes, int n_in,
                              void* d_out, int out_size, void* d_ws, size_t ws_size,
                              hipStream_t stream)
{
    const float* x_t   = (const float*)d_in[0];
    const float* state = (const float*)d_in[1];
    const float* Wc    = (const float*)d_in[2];
    const float* Uc    = (const float*)d_in[3];
    const float* bc    = (const float*)d_in[4];
    const float* Wg    = (const float*)d_in[5];
    const float* Ug    = (const float*)d_in[6];
    const float* bg    = (const float*)d_in[7];
    const float* lstep = (const float*)d_in[8];
    const float* gam   = (const float*)d_in[9];
    const float* bet   = (const float*)d_in[10];
    float* out = (float*)d_out;

    // workspace: Wt (32MB) | Acat (64MB) | h (64MB fp32) = 160MB
    char* ws = (char*)d_ws;
    short* Wt   = (short*)ws;
    short* Acat = (short*)(ws + (size_t)32 * 1024 * 1024);
    float* h    = (float*)(ws + (size_t)96 * 1024 * 1024);

    build_wt<<<dim3(Nall / 32, Kdim / 32), 256, 0, stream>>>(Wc, Uc, Wg, Ug, Wt);
    build_acat<<<(Bsz * (Kdim / 8)) / 256, 256, 0, stream>>>(x_t, state, Acat);
    gemm_fused<<<dim3((Bsz / BM) * (Hdim / BNH)), 512, 0, stream>>>(
        Acat, Wt, state, bc, bg, lstep, h);
    ln_k<<<Bsz, 256, 0, stream>>>(h, gam, bet, out);
}